// Round 7
// baseline (591.782 us; speedup 1.0000x reference)
//
#include <hip/hip_runtime.h>
#include <math.h>

#define BATCH 8
#define CCH   256
#define HH    64
#define WW    64
#define NN    4096                    // HH*WW

#define BNC   (BATCH * NN * CCH)      // 8,388,608 elems per tensor
#define WELEMS (3 * 8 * 9 * 256 * 32) // 1,769,472 fp16 weight elems per hi/lo

typedef __bf16   bf16x8 __attribute__((ext_vector_type(8)));
typedef _Float16 f16x8  __attribute__((ext_vector_type(8)));
typedef _Float16 f16x4  __attribute__((ext_vector_type(4)));
typedef float    f32x4  __attribute__((ext_vector_type(4)));

// ---------------------------------------------------------------------------
// Weights: OIHW fp32 -> fp16 hi/lo, layout [conv][cc8][tap9][co256][ci32]
// ---------------------------------------------------------------------------
__global__ void wtrans_kernel(const float* __restrict__ w1,
                              const float* __restrict__ w2,
                              const float* __restrict__ w3,
                              _Float16* __restrict__ Whi,
                              _Float16* __restrict__ Wlo) {
    int e = blockIdx.x * 256 + threadIdx.x;      // 0 .. WELEMS-1
    int t = e;
    const int ci  = t & 31;  t >>= 5;
    const int co  = t & 255; t >>= 8;
    const int tap = t % 9;   t /= 9;
    const int cc  = t & 7;   t >>= 3;
    const int conv = t;
    const float* src = (conv == 0) ? w1 : (conv == 1) ? w2 : w3;
    const float v = src[co * 2304 + (cc * 32 + ci) * 9 + tap];
    const _Float16 h = (_Float16)v;
    Whi[e] = h;
    Wlo[e] = (_Float16)(v - (float)h);
}

// ---------------------------------------------------------------------------
// X: [b][ci][h][w] fp32 -> Xhi/Xlo fp16 [b][h][w][ci]  (transpose via LDS)
// ---------------------------------------------------------------------------
__global__ __launch_bounds__(256)
void xsplit_kernel(const float* __restrict__ X,
                   _Float16* __restrict__ Xhi, _Float16* __restrict__ Xlo) {
    __shared__ float T[64][65];
    const int h = blockIdx.x, c0 = blockIdx.y * 64, bb = blockIdx.z;
    const int t = threadIdx.x;
    const int row = t >> 2, q = (t & 3) * 16;
#pragma unroll
    for (int k = 0; k < 4; ++k) {
        float4 v = *(const float4*)&X[(((size_t)bb * CCH + c0 + row) * HH + h) * WW + q + k * 4];
        *(float4*)&T[row][q + k * 4] = v;
    }
    __syncthreads();
    f16x8 h0, h1, l0, l1;
#pragma unroll
    for (int j = 0; j < 8; ++j) {
        float v = T[q + j][row];
        _Float16 hh = (_Float16)v;
        h0[j] = hh; l0[j] = (_Float16)(v - (float)hh);
    }
#pragma unroll
    for (int j = 0; j < 8; ++j) {
        float v = T[q + 8 + j][row];
        _Float16 hh = (_Float16)v;
        h1[j] = hh; l1[j] = (_Float16)(v - (float)hh);
    }
    const size_t g = (((size_t)bb * HH + h) * WW + row) * CCH + c0 + q;
    *(f16x8*)(Xhi + g) = h0;  *(f16x8*)(Xhi + g + 8) = h1;
    *(f16x8*)(Xlo + g) = l0;  *(f16x8*)(Xlo + g + 8) = l1;
}

// ---------------------------------------------------------------------------
// MFMA implicit-GEMM conv 3x3 SAME + bias, v6 (unchanged from round 6).
// ---------------------------------------------------------------------------
__global__ __launch_bounds__(512, 2)
void conv_mfma_kernel(const _Float16* __restrict__ Xhi, const _Float16* __restrict__ Xlo,
                      const _Float16* __restrict__ Whi, const _Float16* __restrict__ Wlo,
                      const float* __restrict__ b1, const float* __restrict__ b2,
                      const float* __restrict__ b3,
                      __bf16* __restrict__ Qhi, __bf16* __restrict__ Qlo,
                      __bf16* __restrict__ Khi, __bf16* __restrict__ Klo,
                      float* __restrict__ Dws) {
    const int h0   = blockIdx.x * 2;
    const int bb   = blockIdx.y;
    const int conv = blockIdx.z;
    const int tid  = threadIdx.x;
    const int wave = tid >> 6;
    const int lane = tid & 63;
    const int quad = lane >> 4;
    const int l16  = lane & 15;
    const int mg   = wave >> 2;
    const int ng   = wave & 3;

    // [4 rows][66 cols][32 ch], col 0 and 65 are zero pads
    __shared__ _Float16 XsH[4 * 66 * 32];
    __shared__ _Float16 XsL[4 * 66 * 32];

    const bool threePass = (conv < 2);
    const float* bias = (conv == 0) ? b1 : (conv == 1) ? b2 : b3;

    f32x4 acc[4][4];
#pragma unroll
    for (int j = 0; j < 4; ++j) {
        const float bv = bias[ng * 64 + j * 16 + l16];
#pragma unroll
        for (int i = 0; i < 4; ++i) acc[i][j] = (f32x4){bv, bv, bv, bv};
    }

    const f16x8 zf = {0, 0, 0, 0, 0, 0, 0, 0};
    const int xrow = tid >> 7;
    const int xw   = (tid >> 1) & 63;
    const int xch  = (tid & 1) * 16;
    const int xc0  = (tid & 1) * 2;       // first 16B-chunk index (0 or 2)

    // zero the pad columns once (cols 0 and 65, all 4 rows, all 32 ch)
    if (tid < 256) {
        const int zr = tid >> 6, zc = ((tid >> 5) & 1) ? 65 : 0, zch = tid & 31;
        XsH[(zr * 66 + zc) * 32 + zch] = (_Float16)0;
        XsL[(zr * 66 + zc) * 32 + zch] = (_Float16)0;
    }

    // per-lane LDS read bases for dw = 0,1,2 (col = i*16 + l16 + dw)
    int xb[3];
#pragma unroll
    for (int dw = 0; dw < 3; ++dw)
        xb[dw] = mg * 2112 + (l16 + dw) * 32 + ((quad ^ ((l16 + dw) & 3)) * 8);

    // W direct-from-global: per-lane offset inside a tap block [co256][ci32]
    const int wloff = (ng * 64 + l16) * 32 + quad * 8;
    const _Float16* WhB = Whi + (size_t)conv * 589824;
    const _Float16* WlB = Wlo + (size_t)conv * 589824;

    // W tap double-buffers: wbh/wbl[parity][j]
    f16x8 wbh[2][4], wbl[2][4];
#pragma unroll
    for (int j = 0; j < 4; ++j) {
        wbh[0][j] = *(const f16x8*)(WhB + wloff + j * 512);
        wbl[0][j] = zf;
        if (threePass) wbl[0][j] = *(const f16x8*)(WlB + wloff + j * 512);
    }

    for (int cc2 = 0; cc2 < 4; ++cc2) {
#pragma unroll
        for (int ccp = 0; ccp < 2; ++ccp) {
            const int cc = cc2 * 2 + ccp;
            __syncthreads();                  // previous cc's LDS reads done
            {
                const int h = h0 - 1 + xrow;
                f16x8 a0 = zf, a1 = zf, b0 = zf, b1v = zf;
                if ((unsigned)h < (unsigned)HH) {
                    const size_t g = (((size_t)bb * HH + h) * WW + xw) * CCH + cc * 32 + xch;
                    a0 = *(const f16x8*)(Xhi + g);  a1 = *(const f16x8*)(Xhi + g + 8);
                    if (threePass) { b0 = *(const f16x8*)(Xlo + g);  b1v = *(const f16x8*)(Xlo + g + 8); }
                }
                // write col xw+1 (data cols are 1..64), swizzle units by (col&3)
                const int col = xw + 1;
                const int lbase = (xrow * 66 + col) * 32;
                const int s3 = col & 3;
                *(f16x8*)&XsH[lbase + ((xc0 ^ s3) * 8)]       = a0;
                *(f16x8*)&XsH[lbase + (((xc0 + 1) ^ s3) * 8)] = a1;
                if (threePass) {
                    *(f16x8*)&XsL[lbase + ((xc0 ^ s3) * 8)]       = b0;
                    *(f16x8*)&XsL[lbase + (((xc0 + 1) ^ s3) * 8)] = b1v;
                }
            }
            __syncthreads();                  // X tile visible

#pragma unroll
            for (int tap = 0; tap < 9; ++tap) {
                const int p  = (ccp + tap) & 1;   // compile-time parity
                const int np = p ^ 1;
                // ---- prefetch next tap's W fragments into ping buffer ----
                {
                    const int nst = cc * 9 + tap + 1;          // 1..72
                    const size_t nb = (size_t)(nst == 72 ? 0 : nst) * 8192 + wloff;
#pragma unroll
                    for (int j = 0; j < 4; ++j) {
                        wbh[np][j] = *(const f16x8*)(WhB + nb + j * 512);
                        if (threePass) wbl[np][j] = *(const f16x8*)(WlB + nb + j * 512);
                    }
                }
                // ---- LDS A fragments ----
                const int dh = tap / 3, dw = tap % 3;          // compile-time
                f16x8 ah[4], al[4];
#pragma unroll
                for (int i = 0; i < 4; ++i) {
                    const int off = xb[dw] + dh * 2112 + i * 512;  // imm-folded
                    ah[i] = *(const f16x8*)&XsH[off];
                    if (threePass) al[i] = *(const f16x8*)&XsL[off];
                }
                // ---- MFMA with pong buffer (filled one full tap ago) ----
#pragma unroll
                for (int j = 0; j < 4; ++j) {
                    if (threePass) {
#pragma unroll
                        for (int i = 0; i < 4; ++i) {
                            acc[i][j] = __builtin_amdgcn_mfma_f32_16x16x32_f16(ah[i], wbh[p][j], acc[i][j], 0, 0, 0);
                            acc[i][j] = __builtin_amdgcn_mfma_f32_16x16x32_f16(al[i], wbh[p][j], acc[i][j], 0, 0, 0);
                            acc[i][j] = __builtin_amdgcn_mfma_f32_16x16x32_f16(ah[i], wbl[p][j], acc[i][j], 0, 0, 0);
                        }
                    } else {
#pragma unroll
                        for (int i = 0; i < 4; ++i)
                            acc[i][j] = __builtin_amdgcn_mfma_f32_16x16x32_f16(ah[i], wbh[p][j], acc[i][j], 0, 0, 0);
                    }
                }
            }
        }
    }

    const size_t nb = (size_t)bb * NN + (size_t)(h0 + mg) * 64;
    if (threePass) {
        __bf16* Hi = conv ? Khi : Qhi;
        __bf16* Lo = conv ? Klo : Qlo;
#pragma unroll
        for (int i = 0; i < 4; ++i) {
            const int wx0 = i * 16 + quad * 4;
#pragma unroll
            for (int j = 0; j < 4; ++j) {
                const int co = ng * 64 + j * 16 + l16;
#pragma unroll
                for (int r = 0; r < 4; ++r) {
                    const float v = acc[i][j][r];
                    const size_t idx = (nb + wx0 + r) * CCH + co;
                    const __bf16 hq = (__bf16)v;
                    Hi[idx] = hq;
                    Lo[idx] = (__bf16)(v - (float)hq);
                }
            }
        }
    } else {
#pragma unroll
        for (int i = 0; i < 4; ++i) {
            const int wx0 = i * 16 + quad * 4;
#pragma unroll
            for (int j = 0; j < 4; ++j) {
                const int co = ng * 64 + j * 16 + l16;
#pragma unroll
                for (int r = 0; r < 4; ++r)
                    Dws[(nb + wx0 + r) * CCH + co] = acc[i][j][r];
            }
        }
    }
}

// ---------------------------------------------------------------------------
// Transpose D (fp32 [b][n][c]) -> Vt (fp16 [b][c][n]).
// ---------------------------------------------------------------------------
__global__ __launch_bounds__(256)
void transpose_v_kernel(const float* __restrict__ D, _Float16* __restrict__ Vt) {
    __shared__ float T[64][65];
    const int n0 = blockIdx.x * 64, c0 = blockIdx.y * 64, bb = blockIdx.z;
    const int t = threadIdx.x;
    const int row = t >> 2, q = (t & 3) * 16;
#pragma unroll
    for (int k = 0; k < 4; ++k) {
        float4 v = *(const float4*)(D + ((size_t)bb * NN + n0 + row) * CCH + c0 + q + k * 4);
        *(float4*)&T[row][q + k * 4] = v;
    }
    __syncthreads();
    f16x8 o0, o1;
#pragma unroll
    for (int j = 0; j < 8; ++j) o0[j] = (_Float16)T[q + j][row];
#pragma unroll
    for (int j = 0; j < 8; ++j) o1[j] = (_Float16)T[q + 8 + j][row];
    _Float16* dst = Vt + ((size_t)bb * CCH + c0 + row) * NN + n0 + q;
    *(f16x8*)dst = o0;
    *(f16x8*)(dst + 8) = o1;
}

// ---------------------------------------------------------------------------
// MFMA flash attention v7: attn was LDS-volume-bound (each of 8 waves read
// the full K chunks AND the full V tile -> ~1.8MB LDS/tile/CU, LDS unit the
// saturated pipe at MfmaUtil 41%).  Changes:
//  - PV channel-ownership: wave w owns O^T[c in w*32..+32][all 128 q].
//    vf reads 64 -> 8 per wave; pf reads all waves' P (4 -> 32).  Per-q
//    softmax scale / 1/l broadcast via tiny LDS arrays Ssc/Linv.
//  - V read DIRECT from global Vt (XCD-L2-resident, each byte now read once
//    per CU): Vs 64KB LDS + vload/vwrite + V barrier removed.
//  - Freed LDS -> K chunk double-buffer (2x32KB): ONE barrier per chunk.
//    Barriers/tile 8 -> 6.  LDS total 101376B, 1 block/CU, grid 256,
//    batch = blockIdx&7 pins batch -> XCD.
// ---------------------------------------------------------------------------
__global__ __launch_bounds__(512, 2)
void attn_mfma_kernel(const __bf16* __restrict__ Qhi, const __bf16* __restrict__ Qlo,
                      const __bf16* __restrict__ Khi, const __bf16* __restrict__ Klo,
                      const _Float16* __restrict__ Vt, const float* __restrict__ alpha_p,
                      float* __restrict__ out) {
    const int bb = blockIdx.x & 7;     // batch -> XCD
    const int qb = blockIdx.x >> 3;    // 0..31
    const int n0 = qb * 128;
    const int tid  = threadIdx.x;
    const int wave = tid >> 6;         // 0..7
    const int lane = tid & 63;
    const int quad = lane >> 4;
    const int l16  = lane & 15;
    const int xq   = l16 & 7;

    extern __shared__ __align__(16) unsigned char smem[];
    // K chunk double buffer: buf p at smem + p*32768 (hi 16KB, lo 16KB)
    _Float16* PwA  = (_Float16*)(smem + 65536);   // 8 waves x [16][136] fp16
    float*    Ssc  = (float*)(smem + 100352);     // per-q rescale factor [128]
    float*    Linv = (float*)(smem + 100864);     // per-q alpha/l at end [128]
    _Float16* Pw   = PwA + wave * (16 * 136);

    // Q resident in registers as B-frags: this wave's 16 q-rows
    bf16x8 qh[8], ql[8];
    {
        const size_t base = ((size_t)bb * NN + n0 + wave * 16 + l16) * CCH + quad * 8;
#pragma unroll
        for (int ks = 0; ks < 8; ++ks) {
            qh[ks] = *(const bf16x8*)(Qhi + base + ks * 32);
            ql[ks] = *(const bf16x8*)(Qlo + base + ks * 32);
        }
    }

    // O^T accumulators, channel-ownership: c = wave*32 + cf*16 + quad*4 + r,
    // q = n0 + qt*16 + l16
    f32x4 Oacc[2][8];
#pragma unroll
    for (int cf = 0; cf < 2; ++cf)
#pragma unroll
        for (int qt = 0; qt < 8; ++qt) Oacc[cf][qt] = (f32x4){0.f, 0.f, 0.f, 0.f};
    float m_i = -INFINITY, l_i = 0.f;

    // K staging coords: 4 thr/row (128 rows), 2x16B units each per hi/lo
    const int krow = tid >> 2, kq4 = tid & 3;

    bf16x8 kph[2], kpl[2];     // K-chunk prefetch regs

    auto kload = [&](int m0_, int cc_) {
#pragma unroll
        for (int i = 0; i < 2; ++i) {
            const int u = kq4 * 2 + i;
            const size_t g = ((size_t)bb * NN + m0_ + krow) * CCH + cc_ * 64 + u * 8;
            kph[i] = *(const bf16x8*)(Khi + g);
            kpl[i] = *(const bf16x8*)(Klo + g);
        }
    };
    auto kwrite = [&](__bf16* H, __bf16* L) {
#pragma unroll
        for (int i = 0; i < 2; ++i) {
            const int u = kq4 * 2 + i;
            const int lo = krow * 64 + ((u ^ (krow & 7)) * 8);
            *(bf16x8*)&H[lo] = kph[i];
            *(bf16x8*)&L[lo] = kpl[i];
        }
    };

    f32x4 Sacc[8];
    auto schunk = [&](int cc, const __bf16* KH, const __bf16* KL) {
#pragma unroll
        for (int ks = 0; ks < 2; ++ks) {
            const int kq = cc * 2 + ks;
#pragma unroll
            for (int kvt = 0; kvt < 8; ++kvt) {
                const int off = (kvt * 16 + l16) * 64 + (((ks * 4 + quad) ^ xq) * 8);
                const bf16x8 kh = *(const bf16x8*)&KH[off];
                const bf16x8 kl = *(const bf16x8*)&KL[off];
                Sacc[kvt] = __builtin_amdgcn_mfma_f32_16x16x32_bf16(kh, qh[kq], Sacc[kvt], 0, 0, 0);
                Sacc[kvt] = __builtin_amdgcn_mfma_f32_16x16x32_bf16(kl, qh[kq], Sacc[kvt], 0, 0, 0);
                Sacc[kvt] = __builtin_amdgcn_mfma_f32_16x16x32_bf16(kh, ql[kq], Sacc[kvt], 0, 0, 0);
            }
        }
    };

    // prologue: stage K chunk0 of tile 0 into buf0
    kload(0, 0);
    kwrite((__bf16*)smem, (__bf16*)(smem + 16384));
    __syncthreads();

    for (int t = 0; t < 32; ++t) {
        const int m0 = t * 128;
#pragma unroll
        for (int kvt = 0; kvt < 8; ++kvt) Sacc[kvt] = (f32x4){0.f, 0.f, 0.f, 0.f};

        // ---- S chunks 0..3, K double-buffered: ONE barrier per chunk ----
#pragma unroll
        for (int cc = 0; cc < 4; ++cc) {
            const int p = cc & 1;
            const __bf16* KH = (const __bf16*)(smem + p * 32768);
            const __bf16* KL = (const __bf16*)(smem + p * 32768 + 16384);
            __bf16* WH = (__bf16*)(smem + (p ^ 1) * 32768);
            __bf16* WL = (__bf16*)(smem + (p ^ 1) * 32768 + 16384);
            // prefetch next chunk (cc==3: chunk0 of next tile) into regs
            kload(cc < 3 ? m0 : ((t == 31) ? 0 : m0 + 128), (cc + 1) & 3);
            schunk(cc, KH, KL);        // consume buf[p]
            kwrite(WH, WL);            // fill buf[p^1] (chunk cc-1 readers
                                       // finished before this phase's entry)
            __syncthreads();           // buf[p^1] visible for next phase
        }

        // ---- V fragments direct from global (L2-resident tile) ----
        f16x8 vf[2][4];
#pragma unroll
        for (int cf = 0; cf < 2; ++cf)
#pragma unroll
            for (int kvf = 0; kvf < 4; ++kvf)
                vf[cf][kvf] = *(const f16x8*)(Vt +
                    ((size_t)bb * CCH + wave * 32 + cf * 16 + l16) * NN +
                    m0 + kvf * 32 + quad * 8);

        // ---- online softmax over 128 kv (this wave's 16 q-rows) ----
        float mx = -INFINITY;
#pragma unroll
        for (int kvt = 0; kvt < 8; ++kvt)
#pragma unroll
            for (int r = 0; r < 4; ++r) mx = fmaxf(mx, Sacc[kvt][r]);
        mx = fmaxf(mx, __shfl_xor(mx, 16, 64));
        mx = fmaxf(mx, __shfl_xor(mx, 32, 64));
        const float mnew = fmaxf(m_i, mx);
        float rs = 0.f;
#pragma unroll
        for (int kvt = 0; kvt < 8; ++kvt) {
            f16x4 pw;
#pragma unroll
            for (int r = 0; r < 4; ++r) {
                const float p = __expf(Sacc[kvt][r] - mnew);
                rs += p;
                pw[r] = (_Float16)p;
            }
            *(f16x4*)&Pw[l16 * 136 + kvt * 16 + quad * 4] = pw;
        }
        rs += __shfl_xor(rs, 16, 64);
        rs += __shfl_xor(rs, 32, 64);
        const float scale = __expf(m_i - mnew);    // 0 on first tile
        if (quad == 0) Ssc[wave * 16 + l16] = scale;
        l_i = l_i * scale + rs;
        m_i = mnew;
        __syncthreads();               // Pw + Ssc visible to all waves

        // ---- rescale O by per-q factors (broadcast reads) ----
        float sc[8];
#pragma unroll
        for (int qt = 0; qt < 8; ++qt) sc[qt] = Ssc[qt * 16 + l16];
#pragma unroll
        for (int cf = 0; cf < 2; ++cf)
#pragma unroll
            for (int qt = 0; qt < 8; ++qt) {
                Oacc[cf][qt][0] *= sc[qt];
                Oacc[cf][qt][1] *= sc[qt];
                Oacc[cf][qt][2] *= sc[qt];
                Oacc[cf][qt][3] *= sc[qt];
            }

        // ---- O^T += V^T P^T over ALL 128 q (channel-ownership) ----
#pragma unroll
        for (int qt = 0; qt < 8; ++qt) {
            const _Float16* Pq = PwA + qt * (16 * 136);
            f16x8 pf[4];
#pragma unroll
            for (int kvf = 0; kvf < 4; ++kvf)
                pf[kvf] = *(const f16x8*)&Pq[l16 * 136 + kvf * 32 + quad * 8];
#pragma unroll
            for (int cf = 0; cf < 2; ++cf)
#pragma unroll
                for (int kvf = 0; kvf < 4; ++kvf)
                    Oacc[cf][qt] = __builtin_amdgcn_mfma_f32_16x16x32_f16(vf[cf][kvf], pf[kvf], Oacc[cf][qt], 0, 0, 0);
        }
        __syncthreads();               // Pw reads done before next softmax
    }

    // ---- epilogue: per-q 1/l broadcast, *alpha, write out[b][c][n] ----
    const float alpha = *alpha_p;
    if (quad == 0) Linv[wave * 16 + l16] = alpha / l_i;
    __syncthreads();
#pragma unroll
    for (int qt = 0; qt < 8; ++qt) {
        const float inv = Linv[qt * 16 + l16];
#pragma unroll
        for (int cf = 0; cf < 2; ++cf)
#pragma unroll
            for (int r = 0; r < 4; ++r) {
                const int c = wave * 32 + cf * 16 + quad * 4 + r;
                out[((size_t)bb * CCH + c) * NN + n0 + qt * 16 + l16] = Oacc[cf][qt][r] * inv;
            }
    }
}

// ---------------------------------------------------------------------------
extern "C" void kernel_launch(void* const* d_in, const int* in_sizes, int n_in,
                              void* d_out, int out_size, void* d_ws, size_t ws_size,
                              hipStream_t stream) {
    const float* X  = (const float*)d_in[0];
    const float* w1 = (const float*)d_in[1];
    const float* b1 = (const float*)d_in[2];
    const float* w2 = (const float*)d_in[3];
    const float* b2 = (const float*)d_in[4];
    const float* w3 = (const float*)d_in[5];
    const float* b3 = (const float*)d_in[6];
    const float* alpha = (const float*)d_in[7];
    float* out = (float*)d_out;

    float*    Dws = (float*)d_ws;
    __bf16*   Qhi = (__bf16*)(Dws + (size_t)BNC);
    __bf16*   Qlo = Qhi + (size_t)BNC;
    __bf16*   Khi = Qlo + (size_t)BNC;
    __bf16*   Klo = Khi + (size_t)BNC;
    _Float16* Vt  = (_Float16*)(Klo + (size_t)BNC);
    _Float16* Xhi = Vt + (size_t)BNC;
    _Float16* Xlo = Xhi + (size_t)BNC;
    _Float16* Whi = Xlo + (size_t)BNC;
    _Float16* Wlo = Whi + (size_t)WELEMS;

    wtrans_kernel<<<dim3(WELEMS / 256), 256, 0, stream>>>(w1, w2, w3, Whi, Wlo);

    xsplit_kernel<<<dim3(HH, CCH / 64, BATCH), 256, 0, stream>>>(X, Xhi, Xlo);

    conv_mfma_kernel<<<dim3(HH / 2, BATCH, 3), 512, 0, stream>>>(
        Xhi, Xlo, Whi, Wlo, b1, b2, b3, Qhi, Qlo, Khi, Klo, Dws);

    transpose_v_kernel<<<dim3(NN / 64, CCH / 64, BATCH), 256, 0, stream>>>(Dws, Vt);

    // dynamic LDS: K dbuf 64KB + P 34KB + Ssc/Linv 1KB = 101376 B
    attn_mfma_kernel<<<dim3(256), 512, 101376, stream>>>(
        Qhi, Qlo, Khi, Klo, Vt, alpha, out);
}